// Round 1
// 1011.574 us; speedup vs baseline: 1.1069x; 1.1069x over previous
//
#include <hip/hip_runtime.h>

// Problem constants (fixed for LREN_78847009620091):
// B=8192, T=64, D=64, H=256, L=64, NS=64, K=D+L=128
// out = [enc_gt (8192*64*128 f32), enc_traj (8192*64*128 f32)]

typedef __attribute__((ext_vector_type(8))) short short8;   // 8 bf16 (4 VGPRs)
typedef __attribute__((ext_vector_type(4))) short sshort4;  // 4 bf16 (8B)
typedef __attribute__((ext_vector_type(4))) float floatx4;  // MFMA accumulator

#define DEV __device__ __forceinline__

DEV short f2bf(float f) {  // fp32 -> bf16 RNE
  unsigned u = __builtin_bit_cast(unsigned, f);
  unsigned r = u + 0x7fffu + ((u >> 16) & 1u);
  return (short)(r >> 16);
}

DEV floatx4 zero4() { return (floatx4){0.f, 0.f, 0.f, 0.f}; }

constexpr long ROWS     = 524288;    // B*T
constexpr long GT_ELEMS = 67108864;  // ROWS*128, offset of enc_traj in out
constexpr int  HS_STRIDE = 264;      // 256 + 8 bf16 pad (16B-aligned rows, bank-spread)
constexpr int  AS_STRIDE = 136;      // 128 + 8 bf16 pad

// ---------------------------------------------------------------------------
// prep: weight->bf16 fragment layout;  Ppow[0]=I, Ppow[1]=ko_W
// Fragment layout: Wf[((nt*KT + kt)*64 + lane)*8 + j] = W[kt*32+(lane>>4)*8+j][nt*16+(lane&15)]
// ---------------------------------------------------------------------------
__global__ void prep_kernel(const float* __restrict__ W0, const float* __restrict__ W1,
                            const float* __restrict__ W2, const float* __restrict__ koW,
                            float* __restrict__ Ppow, short* __restrict__ Wf0,
                            short* __restrict__ Wf1, short* __restrict__ Wf2) {
  int g = blockIdx.x * 256 + threadIdx.x;
  if (g < 2048) {                       // W0: K=64 (KT=2), N=256
    int lane = g & 63; int ntkt = g >> 6;
    int n  = ((ntkt >> 1) << 4) + (lane & 15);
    int k0 = (ntkt & 1) * 32 + (lane >> 4) * 8;
    short8 v;
    #pragma unroll
    for (int j = 0; j < 8; ++j) v[j] = f2bf(W0[(k0 + j) * 256 + n]);
    *(short8*)(Wf0 + g * 8) = v;
  } else if (g < 10240) {               // W1: K=256 (KT=8), N=256
    int h = g - 2048;
    int lane = h & 63; int ntkt = h >> 6;
    int n  = ((ntkt >> 3) << 4) + (lane & 15);
    int k0 = (ntkt & 7) * 32 + (lane >> 4) * 8;
    short8 v;
    #pragma unroll
    for (int j = 0; j < 8; ++j) v[j] = f2bf(W1[(k0 + j) * 256 + n]);
    *(short8*)(Wf1 + h * 8) = v;
  } else if (g < 12288) {               // W2: K=256 (KT=8), N=64
    int h = g - 10240;
    int lane = h & 63; int ntkt = h >> 6;
    int n  = ((ntkt >> 3) << 4) + (lane & 15);
    int k0 = (ntkt & 7) * 32 + (lane >> 4) * 8;
    short8 v;
    #pragma unroll
    for (int j = 0; j < 8; ++j) v[j] = f2bf(W2[(k0 + j) * 64 + n]);
    *(short8*)(Wf2 + h * 8) = v;
  } else if (g < 12288 + 8192) {        // P0 = I, P1 = ko_W (fp32)
    int h = g - 12288;
    if (h < 4096) {
      int e = h * 4; int row = e >> 7; int c = e & 127;
      float4 v;
      v.x = (c     == row) ? 1.f : 0.f;
      v.y = (c + 1 == row) ? 1.f : 0.f;
      v.z = (c + 2 == row) ? 1.f : 0.f;
      v.w = (c + 3 == row) ? 1.f : 0.f;
      ((float4*)Ppow)[h] = v;
    } else {
      ((float4*)(Ppow + 16384))[h - 4096] = ((const float4*)koW)[h - 4096];
    }
  }
}

// ---------------------------------------------------------------------------
// pow_step: P[base+j] = P[j] @ P[base], j = 1..cnt  (fp32, 128x128x128 each)
// grid = cnt*4 blocks; block handles 32 rows of one product.
// ---------------------------------------------------------------------------
__global__ __launch_bounds__(256) void pow_step(float* Ppow, int base) {
  __shared__ float Bs[128 * 128];   // 64 KB: P[base] staged
  const int tid = threadIdx.x;
  const int j  = (blockIdx.x >> 2) + 1;
  const int qt = blockIdx.x & 3;
  const float* Bm = Ppow + (long)base * 16384;
  #pragma unroll
  for (int i = 0; i < 16; ++i) {
    int f4 = tid + 256 * i;
    ((float4*)Bs)[f4] = ((const float4*)Bm)[f4];
  }
  __syncthreads();
  const int row = qt * 32 + (tid >> 3);
  const int cg  = (tid & 7) * 16;
  const float* Arow = Ppow + (long)j * 16384 + row * 128;
  float acc[16];
  #pragma unroll
  for (int c = 0; c < 16; ++c) acc[c] = 0.f;
  for (int kk = 0; kk < 128; kk += 4) {
    float4 a4 = *(const float4*)(Arow + kk);
    #pragma unroll
    for (int u = 0; u < 4; ++u) {
      float a = (u == 0) ? a4.x : (u == 1) ? a4.y : (u == 2) ? a4.z : a4.w;
      const float* brow = Bs + (kk + u) * 128 + cg;
      #pragma unroll
      for (int c = 0; c < 16; ++c) acc[c] = fmaf(a, brow[c], acc[c]);
    }
  }
  float* Out = Ppow + (long)(base + j) * 16384 + row * 128 + cg;
  #pragma unroll
  for (int c4 = 0; c4 < 4; ++c4) {
    float4 o; o.x = acc[c4*4]; o.y = acc[c4*4+1]; o.z = acc[c4*4+2]; o.w = acc[c4*4+3];
    *(float4*)(Out + c4 * 4) = o;
  }
}

// ---------------------------------------------------------------------------
// convP: powers (fp32, [t][k][c]) -> bf16 B-fragment layout for N=8192, K=128
// Pf[((nt*4 + kt)*64 + lane)*8 + j] = P[t][kt*32+(lane>>4)*8+j][c], n=t*128+c
// ---------------------------------------------------------------------------
__global__ void convP_kernel(const float* __restrict__ Ppow, short* __restrict__ Pf) {
  int g = blockIdx.x * 256 + threadIdx.x;  // 131072 tasks
  int lane = g & 63;
  int kt   = (g >> 6) & 3;
  int nt   = g >> 8;
  int n  = nt * 16 + (lane & 15);
  int t  = n >> 7, c = n & 127;
  int k0 = kt * 32 + (lane >> 4) * 8;
  short8 v;
  #pragma unroll
  for (int j = 0; j < 8; ++j) v[j] = f2bf(Ppow[(long)t * 16384 + (k0 + j) * 128 + c]);
  *(short8*)(Pf + (long)g * 8) = v;
}

// ---------------------------------------------------------------------------
// Fused MLP, N-split across waves:
//   block = 64 rows; wave w owns cols [w*64, w*64+64) (4 nt-tiles) over ALL 4
//   m-tiles. B-frags for the wave's 4 nt are held in regs per kt and reused
//   across the 4 m-tiles -> 4x less L2 weight traffic/block (192KB vs 768KB),
//   4x more MFMA per B-load. A layout: A[m=lane&15][k=(lane>>4)*8+j];
//   C/D: col=lane&15, row=(lane>>4)*4+reg.  H round-trips through LDS.
// ---------------------------------------------------------------------------
__global__ __launch_bounds__(256, 4) void mlp_kernel(const float* __restrict__ x,
    const short* __restrict__ Wf0, const float* __restrict__ b0,
    const short* __restrict__ Wf1, const float* __restrict__ b1,
    const short* __restrict__ Wf2, float* __restrict__ out) {
  __shared__ short Hs[64 * HS_STRIDE];  // 33 KB
  const int tid  = threadIdx.x;
  const int lane = tid & 63;
  const int wave = tid >> 6;
  const int l15  = lane & 15;
  const int q    = lane >> 4;
  const int ntg  = wave * 4;            // wave's nt base (of 16)
  const long rowBase = (long)blockIdx.x * 64;

  // enc_gt[:, :64] = x  (exact fp32 copy; also warms x tile into L1)
  #pragma unroll
  for (int i = 0; i < 4; ++i) {
    int f4 = tid + 256 * i;
    int r = f4 >> 4, c4 = f4 & 15;
    float4 v = ((const float4*)(x + (rowBase + r) * 64))[c4];
    ((float4*)(out + (rowBase + r) * 128))[c4] = v;
  }

  floatx4 acc[4][4];   // [m][nt]
  #pragma unroll
  for (int m = 0; m < 4; ++m)
    #pragma unroll
    for (int nt = 0; nt < 4; ++nt) acc[m][nt] = zero4();

  // ---- Layer 0: H1 = relu(x @ W0 + b0), K=64 ----
  #pragma unroll
  for (int kt = 0; kt < 2; ++kt) {
    short8 bfr[4];
    #pragma unroll
    for (int nt = 0; nt < 4; ++nt)
      bfr[nt] = *(const short8*)(Wf0 + (((ntg + nt) * 2 + kt) * 64 + lane) * 8);
    #pragma unroll
    for (int m = 0; m < 4; ++m) {
      const float* ap = x + (rowBase + m * 16 + l15) * 64 + kt * 32 + q * 8;
      float4 a0 = ((const float4*)ap)[0];
      float4 a1 = ((const float4*)ap)[1];
      short8 af;
      af[0]=f2bf(a0.x); af[1]=f2bf(a0.y); af[2]=f2bf(a0.z); af[3]=f2bf(a0.w);
      af[4]=f2bf(a1.x); af[5]=f2bf(a1.y); af[6]=f2bf(a1.z); af[7]=f2bf(a1.w);
      #pragma unroll
      for (int nt = 0; nt < 4; ++nt)
        acc[m][nt] = __builtin_amdgcn_mfma_f32_16x16x32_bf16(af, bfr[nt], acc[m][nt], 0, 0, 0);
    }
  }
  #pragma unroll
  for (int nt = 0; nt < 4; ++nt) {
    int col = (ntg + nt) * 16 + l15;
    float bias = b0[col];
    #pragma unroll
    for (int m = 0; m < 4; ++m) {
      #pragma unroll
      for (int r = 0; r < 4; ++r) {
        float v = acc[m][nt][r] + bias;
        Hs[(m * 16 + q * 4 + r) * HS_STRIDE + col] = f2bf(v > 0.f ? v : 0.f);
      }
      acc[m][nt] = zero4();
    }
  }
  __syncthreads();

  // ---- Layer 1: H2 = relu(H1 @ W1 + b1), K=256 ----
  #pragma unroll
  for (int kt = 0; kt < 8; ++kt) {
    short8 bfr[4];
    #pragma unroll
    for (int nt = 0; nt < 4; ++nt)
      bfr[nt] = *(const short8*)(Wf1 + (((ntg + nt) * 8 + kt) * 64 + lane) * 8);
    #pragma unroll
    for (int m = 0; m < 4; ++m) {
      short8 af = *(const short8*)(Hs + (m * 16 + l15) * HS_STRIDE + kt * 32 + q * 8);
      #pragma unroll
      for (int nt = 0; nt < 4; ++nt)
        acc[m][nt] = __builtin_amdgcn_mfma_f32_16x16x32_bf16(af, bfr[nt], acc[m][nt], 0, 0, 0);
    }
  }
  __syncthreads();  // all H1 reads done before overwrite
  #pragma unroll
  for (int nt = 0; nt < 4; ++nt) {
    int col = (ntg + nt) * 16 + l15;
    float bias = b1[col];
    #pragma unroll
    for (int m = 0; m < 4; ++m) {
      #pragma unroll
      for (int r = 0; r < 4; ++r) {
        float v = acc[m][nt][r] + bias;
        Hs[(m * 16 + q * 4 + r) * HS_STRIDE + col] = f2bf(v > 0.f ? v : 0.f);
      }
    }
  }
  __syncthreads();

  // ---- Layer 2: z = H2 @ W2, K=256, N=64; wave w owns cols [w*16, w*16+16) ----
  floatx4 acc2[4];
  #pragma unroll
  for (int m = 0; m < 4; ++m) acc2[m] = zero4();
  #pragma unroll
  for (int kt = 0; kt < 8; ++kt) {
    short8 bfr = *(const short8*)(Wf2 + ((wave * 8 + kt) * 64 + lane) * 8);
    #pragma unroll
    for (int m = 0; m < 4; ++m) {
      short8 af = *(const short8*)(Hs + (m * 16 + l15) * HS_STRIDE + kt * 32 + q * 8);
      acc2[m] = __builtin_amdgcn_mfma_f32_16x16x32_bf16(af, bfr, acc2[m], 0, 0, 0);
    }
  }
  #pragma unroll
  for (int m = 0; m < 4; ++m) {
    #pragma unroll
    for (int r = 0; r < 4; ++r)
      out[(rowBase + m * 16 + q * 4 + r) * 128 + 64 + wave * 16 + l15] = acc2[m][r];
  }
}

// ---------------------------------------------------------------------------
// traj: enc_traj[b, t*128+c] = z0[b,:] . P_t[:,c]  as GEMM M=8192,K=128,N=8192
// z0[b][k] = enc_gt[b*8192 + k] (t=0 slice). Block = 64 rows x 256 cols.
// N-split: wave w owns 4 nt-tiles over all 4 m-tiles; z0 tile staged in LDS
// as bf16 (one coalesced pass) instead of per-wave 32KB-strided reloads.
// ---------------------------------------------------------------------------
__global__ __launch_bounds__(256, 4) void traj_kernel(const float* __restrict__ enc_gt,
    const short* __restrict__ Pf, float* __restrict__ out) {
  __shared__ short As[64 * AS_STRIDE];  // 17.4 KB: 64x128 z0 tile, bf16
  const int tid  = threadIdx.x;
  const int lane = tid & 63;
  const int wave = tid >> 6;
  const int l15  = lane & 15;
  const int q    = lane >> 4;
  const int bb = blockIdx.x >> 5;       // 0..127 row blocks
  const int nb = blockIdx.x & 31;       // 0..31 col blocks (256 cols)
  const long rowBase = (long)bb * 64;
  const int ntg = nb * 16 + wave * 4;   // wave's nt base (of 512 global)

  // stage z0 tile: 64 rows x 128 cols fp32 -> bf16 LDS (coalesced full rows)
  #pragma unroll
  for (int i = 0; i < 8; ++i) {
    int idx = tid + 256 * i;
    int r = idx >> 5, c4 = idx & 31;
    float4 v = ((const float4*)(enc_gt + (rowBase + r) * 8192))[c4];
    sshort4 s;
    s[0] = f2bf(v.x); s[1] = f2bf(v.y); s[2] = f2bf(v.z); s[3] = f2bf(v.w);
    *(sshort4*)(As + r * AS_STRIDE + c4 * 4) = s;
  }
  __syncthreads();

  floatx4 acc[4][4];  // [m][nt]
  #pragma unroll
  for (int m = 0; m < 4; ++m)
    #pragma unroll
    for (int nt = 0; nt < 4; ++nt) acc[m][nt] = zero4();

  #pragma unroll
  for (int kt = 0; kt < 4; ++kt) {
    short8 bfr[4];
    #pragma unroll
    for (int nt = 0; nt < 4; ++nt)
      bfr[nt] = *(const short8*)(Pf + (((long)(ntg + nt) * 4 + kt) * 64 + lane) * 8);
    #pragma unroll
    for (int m = 0; m < 4; ++m) {
      short8 af = *(const short8*)(As + (m * 16 + l15) * AS_STRIDE + kt * 32 + q * 8);
      #pragma unroll
      for (int nt = 0; nt < 4; ++nt)
        acc[m][nt] = __builtin_amdgcn_mfma_f32_16x16x32_bf16(af, bfr[nt], acc[m][nt], 0, 0, 0);
    }
  }
  #pragma unroll
  for (int m = 0; m < 4; ++m) {
    #pragma unroll
    for (int nt = 0; nt < 4; ++nt) {
      long col = (long)(ntg + nt) * 16 + l15;
      #pragma unroll
      for (int r = 0; r < 4; ++r)
        out[GT_ELEMS + (rowBase + m * 16 + q * 4 + r) * 8192 + col] = acc[m][nt][r];
    }
  }
}

// ---------------------------------------------------------------------------
extern "C" void kernel_launch(void* const* d_in, const int* in_sizes, int n_in,
                              void* d_out, int out_size, void* d_ws, size_t ws_size,
                              hipStream_t stream) {
  (void)in_sizes; (void)n_in; (void)out_size; (void)ws_size;
  const float* x   = (const float*)d_in[0];
  const float* W0  = (const float*)d_in[1];
  const float* b0  = (const float*)d_in[2];
  const float* W1  = (const float*)d_in[3];
  const float* b1  = (const float*)d_in[4];
  const float* W2  = (const float*)d_in[5];
  const float* koW = (const float*)d_in[6];
  float* out = (float*)d_out;

  // workspace layout (needs ~6.2 MB):
  char* ws = (char*)d_ws;
  float* Ppow = (float*)ws;                  // 64 * 128*128 fp32 = 4 MB
  short* Pf   = (short*)(ws + 4194304);      // 8192*128 bf16 = 2 MB
  short* Wf0  = (short*)(ws + 6291456);      // 32 KB
  short* Wf1  = (short*)(ws + 6324224);      // 128 KB
  short* Wf2  = (short*)(ws + 6455296);      // 32 KB

  hipLaunchKernelGGL(prep_kernel, dim3(80), dim3(256), 0, stream,
                     W0, W1, W2, koW, Ppow, Wf0, Wf1, Wf2);
  const int bases[6] = {1, 2, 4, 8, 16, 32};
  const int cnts[6]  = {1, 2, 4, 8, 16, 31};
  for (int s = 0; s < 6; ++s)
    hipLaunchKernelGGL(pow_step, dim3(cnts[s] * 4), dim3(256), 0, stream, Ppow, bases[s]);
  hipLaunchKernelGGL(convP_kernel, dim3(512), dim3(256), 0, stream, Ppow, Pf);
  hipLaunchKernelGGL(mlp_kernel, dim3(8192), dim3(256), 0, stream,
                     x, Wf0, b0, Wf1, b1, Wf2, out);
  hipLaunchKernelGGL(traj_kernel, dim3(4096), dim3(256), 0, stream, out, Pf, out);
}